// Round 6
// baseline (353.862 us; speedup 1.0000x reference)
//
#include <hip/hip_runtime.h>

#define B_ 4
#define C_ 192
#define H_ 128
#define W_ 128
#define N_ (H_*W_)      // 16384
#define K_ 2048
#define HEADS_ 3
#define HD_ 64
#define HID_ 768
#define NC_ 4           // attention split-K chunks
#define KC_ (K_/NC_)    // 512

typedef __attribute__((ext_vector_type(4))) float f32x4;
typedef __attribute__((ext_vector_type(8))) short bf16x8;

__device__ __forceinline__ unsigned short f2bf(float f){
  unsigned int u = __float_as_uint(f);
  u += 0x7FFFu + ((u >> 16) & 1u);
  return (unsigned short)(u >> 16);
}
__device__ __forceinline__ float bf2f(unsigned short s){
  return __uint_as_float(((unsigned int)s) << 16);
}

__device__ __forceinline__ int load_idx(const unsigned* __restrict__ ip, int pos){
  bool is64 = (ip[1]==0u) & (ip[3]==0u) & (ip[5]==0u) & (ip[7]==0u);
  int v = is64 ? (int)ip[2*pos] : (int)ip[pos];
  return min(max(v, 0), N_-1);
}

// ---------------- LN1: x (B,C,N) -> y (nb,N,C); 256 thr, 4-way C-split ----------------
__global__ __launch_bounds__(256) void k_ln1(const float* __restrict__ x,
    const float* __restrict__ w, const float* __restrict__ bias,
    float* __restrict__ y, int b_off){
  int blk = blockIdx.x;
  int bl = blk >> 8;
  int b  = b_off + bl;
  int n0 = (blk & 255) * 64;
  int t  = threadIdx.x;
  int tok = t & 63, q = t >> 6;
  __shared__ float tile[64][C_+1];
  __shared__ float red[8][64];
  __shared__ float wls[C_], bls[C_];
  if (t < C_){ wls[t] = w[t]; bls[t] = bias[t]; }
  const float* xb = x + (size_t)b*C_*N_ + n0;
  float sum = 0.f, sq = 0.f;
#pragma unroll
  for (int i = 0; i < 48; ++i){
    int c = q + 4*i;
    float v = xb[(size_t)c*N_ + tok];
    tile[tok][c] = v;
    sum += v; sq += v*v;
  }
  red[q][tok] = sum; red[4+q][tok] = sq;
  __syncthreads();
  if (q == 0){
    float s  = red[0][tok]+red[1][tok]+red[2][tok]+red[3][tok];
    float s2 = red[4][tok]+red[5][tok]+red[6][tok]+red[7][tok];
    float mu = s*(1.f/C_);
    float rstd = rsqrtf(s2*(1.f/C_) - mu*mu + 1e-5f);
    red[0][tok] = mu; red[1][tok] = rstd;
  }
  __syncthreads();
  float* yb = y + ((size_t)bl*N_ + n0)*C_;
#pragma unroll
  for (int i = 0; i < 48; ++i){
    int li = t + 256*i;
    int tk = li / C_, c = li - tk*C_;
    yb[li] = (tile[tk][c]-red[0][tk])*red[1][tk]*wls[c] + bls[c];
  }
}

// ---------------- QKV MFMA GEMM with gather ----------------
__global__ __launch_bounds__(256) void k_qkv(const float* __restrict__ y,
    const unsigned* __restrict__ idx, const float* __restrict__ wq,
    unsigned short* __restrict__ qkv, int b_off){
  const int NT = (3*C_)/64;  // 9
  int bid = blockIdx.x;
  int bl  = bid / (16*NT);
  int rem = bid % (16*NT);
  int m0  = (rem / NT) * 128;
  int n0  = (rem % NT) * 64;
  int t = threadIdx.x, lane = t & 63;
  int wv = t >> 6, wm = wv & 1, wn = wv >> 1;
  __shared__ unsigned short Al[128][40];
  __shared__ unsigned short Bl[64][40];
  __shared__ int rows[128];
  if (t < 128) rows[t] = load_idx(idx, (b_off+bl)*K_ + m0 + t);
  __syncthreads();
  f32x4 acc[4][2] = {};
  int l15 = lane & 15, lhi = lane >> 4;
  for (int k0 = 0; k0 < C_; k0 += 32){
    {
      int m = t >> 1;
      const float* src = y + ((size_t)bl*N_ + rows[m])*C_ + k0;
#pragma unroll
      for (int i = 0; i < 4; ++i){
        int kq = (t & 1) + 2*i;
        float4 v = *reinterpret_cast<const float4*>(src + 4*kq);
        ushort4 p; p.x=f2bf(v.x); p.y=f2bf(v.y); p.z=f2bf(v.z); p.w=f2bf(v.w);
        *reinterpret_cast<ushort4*>(&Al[m][4*kq]) = p;
      }
      int n = t >> 2;
      const float* bsrc = wq + (size_t)(n0+n)*C_ + k0;
#pragma unroll
      for (int i = 0; i < 2; ++i){
        int q = (t & 3) + 4*i;
        float4 v = *reinterpret_cast<const float4*>(bsrc + 4*q);
        ushort4 p; p.x=f2bf(v.x); p.y=f2bf(v.y); p.z=f2bf(v.z); p.w=f2bf(v.w);
        *reinterpret_cast<ushort4*>(&Bl[n][4*q]) = p;
      }
    }
    __syncthreads();
    bf16x8 af[4], bfr[2];
#pragma unroll
    for (int mf = 0; mf < 4; ++mf)
      af[mf] = *reinterpret_cast<const bf16x8*>(&Al[wm*64 + mf*16 + l15][lhi*8]);
#pragma unroll
    for (int nf = 0; nf < 2; ++nf)
      bfr[nf] = *reinterpret_cast<const bf16x8*>(&Bl[wn*32 + nf*16 + l15][lhi*8]);
#pragma unroll
    for (int mf = 0; mf < 4; ++mf)
#pragma unroll
      for (int nf = 0; nf < 2; ++nf)
        acc[mf][nf] = __builtin_amdgcn_mfma_f32_16x16x32_bf16(af[mf], bfr[nf], acc[mf][nf], 0,0,0);
    __syncthreads();
  }
#pragma unroll
  for (int mf = 0; mf < 4; ++mf){
    int mb = m0 + wm*64 + mf*16 + lhi*4;
#pragma unroll
    for (int nf = 0; nf < 2; ++nf){
      int n = n0 + wn*32 + nf*16 + l15;
#pragma unroll
      for (int r = 0; r < 4; ++r)
        qkv[((size_t)bl*K_ + mb + r)*(3*C_) + n] = f2bf(acc[mf][nf][r]);
    }
  }
}

// ------- attention split-K: block=(bl,h,64 q rows, chunk c), 4 waves -------
__global__ __launch_bounds__(256) void k_attn(const unsigned short* __restrict__ qkv,
    float* __restrict__ po, float* __restrict__ pml, int nb){
  int bid = blockIdx.x;
  int c   = bid & (NC_-1);
  int qt  = (bid >> 2) & 31;
  int bh  = bid >> 7;
  int h = bh % HEADS_, bl = bh / HEADS_;
  int q0 = qt*64;
  int t = threadIdx.x, lane = t & 63, wv = t >> 6;
  int l15 = lane & 15, lhi = lane >> 4;
  const unsigned short* base = qkv + (size_t)bl*K_*(3*C_) + h*HD_;
  __shared__ unsigned short Ql[64][72];
  __shared__ unsigned short Kl[64][72];
  __shared__ unsigned short Vt[64][72];
  __shared__ unsigned short Pl[4][16][72];
  {
    int r = t >> 2, d0 = (t & 3) * 16;
    const uint4* src = reinterpret_cast<const uint4*>(base + (size_t)(q0+r)*(3*C_) + d0);
    *reinterpret_cast<uint4*>(&Ql[r][d0])   = src[0];
    *reinterpret_cast<uint4*>(&Ql[r][d0+8]) = src[1];
  }
  __syncthreads();
  float m_st[4] = {-1e30f,-1e30f,-1e30f,-1e30f};
  float l_st[4] = {0.f,0.f,0.f,0.f};
  f32x4 o[4] = {};
  for (int kt0 = c*KC_; kt0 < c*KC_ + KC_; kt0 += 64){
    {
      int r = t >> 2, d0 = (t & 3) * 16;
      const uint4* src = reinterpret_cast<const uint4*>(base + (size_t)(kt0+r)*(3*C_) + C_ + d0);
      *reinterpret_cast<uint4*>(&Kl[r][d0])   = src[0];
      *reinterpret_cast<uint4*>(&Kl[r][d0+8]) = src[1];
      int kp = t & 31, vd0 = (t >> 5) * 8, k = 2*kp;
      const ushort4* v0 = reinterpret_cast<const ushort4*>(base + (size_t)(kt0+k)*(3*C_)   + 2*C_ + vd0);
      const ushort4* v1 = reinterpret_cast<const ushort4*>(base + (size_t)(kt0+k+1)*(3*C_) + 2*C_ + vd0);
      ushort4 a0 = v0[0], a1 = v0[1], b0 = v1[0], b1 = v1[1];
      unsigned short va[8] = {a0.x,a0.y,a0.z,a0.w,a1.x,a1.y,a1.z,a1.w};
      unsigned short vb[8] = {b0.x,b0.y,b0.z,b0.w,b1.x,b1.y,b1.z,b1.w};
#pragma unroll
      for (int j = 0; j < 8; ++j){
        unsigned u = (unsigned)va[j] | ((unsigned)vb[j] << 16);
        *reinterpret_cast<unsigned*>(&Vt[vd0+j][k]) = u;
      }
    }
    __syncthreads();
    f32x4 s[4] = {};
#pragma unroll
    for (int kt = 0; kt < 2; ++kt){
      bf16x8 af = *reinterpret_cast<const bf16x8*>(&Ql[wv*16 + l15][kt*32 + lhi*8]);
#pragma unroll
      for (int nt = 0; nt < 4; ++nt){
        bf16x8 bfr = *reinterpret_cast<const bf16x8*>(&Kl[nt*16 + l15][kt*32 + lhi*8]);
        s[nt] = __builtin_amdgcn_mfma_f32_16x16x32_bf16(af, bfr, s[nt], 0,0,0);
      }
    }
    float corr[4];
#pragma unroll
    for (int reg = 0; reg < 4; ++reg){
      float a0 = s[0][reg]*0.125f, a1 = s[1][reg]*0.125f;
      float a2 = s[2][reg]*0.125f, a3 = s[3][reg]*0.125f;
      float mx = fmaxf(fmaxf(a0,a1), fmaxf(a2,a3));
      mx = fmaxf(mx, __shfl_xor(mx, 1));
      mx = fmaxf(mx, __shfl_xor(mx, 2));
      mx = fmaxf(mx, __shfl_xor(mx, 4));
      mx = fmaxf(mx, __shfl_xor(mx, 8));
      float mn = fmaxf(m_st[reg], mx);
      float cr = __expf(m_st[reg] - mn);
      float p0 = __expf(a0 - mn), p1 = __expf(a1 - mn);
      float p2 = __expf(a2 - mn), p3 = __expf(a3 - mn);
      float ls = p0 + p1 + p2 + p3;
      ls += __shfl_xor(ls, 1);
      ls += __shfl_xor(ls, 2);
      ls += __shfl_xor(ls, 4);
      ls += __shfl_xor(ls, 8);
      l_st[reg] = l_st[reg]*cr + ls;
      m_st[reg] = mn; corr[reg] = cr;
      int row = lhi*4 + reg;
      float q0v = __shfl_xor(p0, 1), q1v = __shfl_xor(p1, 1);
      float q2v = __shfl_xor(p2, 1), q3v = __shfl_xor(p3, 1);
      int e = l15 & ~1;
      unsigned uA, uB; int cA, cB;
      if (!(l15 & 1)){
        uA = (unsigned)f2bf(p0) | ((unsigned)f2bf(q0v) << 16); cA = e;
        uB = (unsigned)f2bf(p2) | ((unsigned)f2bf(q2v) << 16); cB = 32 + e;
      } else {
        uA = (unsigned)f2bf(q1v) | ((unsigned)f2bf(p1) << 16); cA = 16 + e;
        uB = (unsigned)f2bf(q3v) | ((unsigned)f2bf(p3) << 16); cB = 48 + e;
      }
      *reinterpret_cast<unsigned*>(&Pl[wv][row][cA]) = uA;
      *reinterpret_cast<unsigned*>(&Pl[wv][row][cB]) = uB;
    }
    __threadfence_block();
#pragma unroll
    for (int nt = 0; nt < 4; ++nt)
#pragma unroll
      for (int reg = 0; reg < 4; ++reg)
        o[nt][reg] *= corr[reg];
#pragma unroll
    for (int kt = 0; kt < 2; ++kt){
      bf16x8 pa = *reinterpret_cast<const bf16x8*>(&Pl[wv][l15][kt*32 + lhi*8]);
#pragma unroll
      for (int nt = 0; nt < 4; ++nt){
        bf16x8 vb = *reinterpret_cast<const bf16x8*>(&Vt[nt*16 + l15][kt*32 + lhi*8]);
        o[nt] = __builtin_amdgcn_mfma_f32_16x16x32_bf16(pa, vb, o[nt], 0,0,0);
      }
    }
    __syncthreads();
  }
  int R = nb*HEADS_*K_;
  int rowb = (bl*HEADS_ + h)*K_;
#pragma unroll
  for (int reg = 0; reg < 4; ++reg){
    int rq = rowb + q0 + wv*16 + lhi*4 + reg;
#pragma unroll
    for (int nt = 0; nt < 4; ++nt)
      po[((size_t)c*R + rq)*HD_ + nt*16 + l15] = o[nt][reg];
    if (l15 == 0)
      *reinterpret_cast<float2*>(pml + 2*((size_t)c*R + rq)) =
          make_float2(m_st[reg], l_st[reg]);
  }
}

// ---------------- merge split-K partials -> ao bf16 (bl,K,C) ----------------
__global__ __launch_bounds__(256) void k_amerge(const float* __restrict__ po,
    const float* __restrict__ pml, unsigned short* __restrict__ ao, int nb){
  int R = nb*HEADS_*K_;
  int row = blockIdx.x*4 + (threadIdx.x >> 6);
  int lane = threadIdx.x & 63;
  float m[NC_], l[NC_];
#pragma unroll
  for (int cc = 0; cc < NC_; ++cc){
    float2 v = *reinterpret_cast<const float2*>(pml + 2*((size_t)cc*R + row));
    m[cc] = v.x; l[cc] = v.y;
  }
  float M = fmaxf(fmaxf(m[0],m[1]), fmaxf(m[2],m[3]));
  float L = 0.f, o = 0.f;
#pragma unroll
  for (int cc = 0; cc < NC_; ++cc){
    float e = __expf(m[cc] - M);
    L += l[cc]*e;
    o += e * po[((size_t)cc*R + row)*HD_ + lane];
  }
  o /= L;
  int q = row & (K_-1);
  int bh = row >> 11;
  int h = bh % HEADS_, bl = bh / HEADS_;
  ao[((size_t)bl*K_ + q)*C_ + h*HD_ + lane] = f2bf(o);
}

// ---------------- proj MFMA GEMM + scatter into y (fp32) ----------------
__global__ __launch_bounds__(256) void k_proj(const unsigned short* __restrict__ ain,
    const unsigned* __restrict__ idx, const float* __restrict__ pw,
    const float* __restrict__ pb, float* __restrict__ y, int b_off){
  const int NT = C_/64;   // 3
  int bid = blockIdx.x;
  int bl  = bid / (16*NT);
  int rem = bid % (16*NT);
  int m0  = (rem / NT) * 128;
  int n0  = (rem % NT) * 64;
  int t = threadIdx.x, lane = t & 63;
  int wv = t >> 6, wm = wv & 1, wn = wv >> 1;
  __shared__ unsigned short Al[128][40];
  __shared__ unsigned short Bl[64][40];
  __shared__ int rows[128];
  if (t < 128) rows[t] = load_idx(idx, (b_off+bl)*K_ + m0 + t);
  __syncthreads();
  f32x4 acc[4][2] = {};
  int l15 = lane & 15, lhi = lane >> 4;
  for (int k0 = 0; k0 < C_; k0 += 32){
    {
      int m = t >> 1;
      const unsigned short* src = ain + ((size_t)bl*K_ + m0 + m)*C_ + k0;
#pragma unroll
      for (int i = 0; i < 4; ++i){
        int kq = (t & 1) + 2*i;
        *reinterpret_cast<ushort4*>(&Al[m][4*kq]) =
            *reinterpret_cast<const ushort4*>(src + 4*kq);
      }
      int n = t >> 2;
      const float* bsrc = pw + (size_t)(n0+n)*C_ + k0;
#pragma unroll
      for (int i = 0; i < 2; ++i){
        int q = (t & 3) + 4*i;
        float4 v = *reinterpret_cast<const float4*>(bsrc + 4*q);
        ushort4 p; p.x=f2bf(v.x); p.y=f2bf(v.y); p.z=f2bf(v.z); p.w=f2bf(v.w);
        *reinterpret_cast<ushort4*>(&Bl[n][4*q]) = p;
      }
    }
    __syncthreads();
    bf16x8 af[4], bfr[2];
#pragma unroll
    for (int mf = 0; mf < 4; ++mf)
      af[mf] = *reinterpret_cast<const bf16x8*>(&Al[wm*64 + mf*16 + l15][lhi*8]);
#pragma unroll
    for (int nf = 0; nf < 2; ++nf)
      bfr[nf] = *reinterpret_cast<const bf16x8*>(&Bl[wn*32 + nf*16 + l15][lhi*8]);
#pragma unroll
    for (int mf = 0; mf < 4; ++mf)
#pragma unroll
      for (int nf = 0; nf < 2; ++nf)
        acc[mf][nf] = __builtin_amdgcn_mfma_f32_16x16x32_bf16(af[mf], bfr[nf], acc[mf][nf], 0,0,0);
    __syncthreads();
  }
#pragma unroll
  for (int mf = 0; mf < 4; ++mf){
    int mb = wm*64 + mf*16 + lhi*4;
#pragma unroll
    for (int nf = 0; nf < 2; ++nf){
      int n = n0 + wn*32 + nf*16 + l15;
      float bv = pb[n];
#pragma unroll
      for (int r = 0; r < 4; ++r)
        y[((size_t)bl*N_ + rows[mb + r])*C_ + n] = acc[mf][nf][r] + bv;
    }
  }
}

// ---------------- residual + LN2 -> ln2t (B,C,N) [== d_out]; 256 thr ----------------
__global__ __launch_bounds__(256) void k_ln2(const float* __restrict__ x,
    const float* __restrict__ y, const float* __restrict__ w,
    const float* __restrict__ bias, float* __restrict__ ln2t, int b_off){
  int blk = blockIdx.x;
  int bl = blk >> 8;
  int b  = b_off + bl;
  int n0 = (blk & 255) * 64;
  int t  = threadIdx.x;
  int tok = t & 63, q = t >> 6;
  __shared__ float tile[64][C_+1];
  __shared__ float red[8][64];
  __shared__ float wls[C_], bls[C_];
  if (t < C_){ wls[t] = w[t]; bls[t] = bias[t]; }
  const float* yb = y + ((size_t)bl*N_ + n0)*C_;
#pragma unroll
  for (int i = 0; i < 48; ++i){
    int li = t + 256*i;
    int tk = li / C_, c = li - tk*C_;
    tile[tk][c] = yb[li];
  }
  __syncthreads();
  const float* xb = x + (size_t)b*C_*N_ + n0;
  float sum = 0.f, sq = 0.f;
#pragma unroll
  for (int i = 0; i < 48; ++i){
    int c = q + 4*i;
    float v = xb[(size_t)c*N_ + tok] + tile[tok][c];
    tile[tok][c] = v;
    sum += v; sq += v*v;
  }
  red[q][tok] = sum; red[4+q][tok] = sq;
  __syncthreads();
  if (q == 0){
    float s  = red[0][tok]+red[1][tok]+red[2][tok]+red[3][tok];
    float s2 = red[4][tok]+red[5][tok]+red[6][tok]+red[7][tok];
    float mu = s*(1.f/C_);
    float rstd = rsqrtf(s2*(1.f/C_) - mu*mu + 1e-5f);
    red[0][tok] = mu; red[1][tok] = rstd;
  }
  __syncthreads();
  float* ob = ln2t + (size_t)b*C_*N_ + n0;
  float mu = red[0][tok], rstd = red[1][tok];
#pragma unroll
  for (int i = 0; i < 48; ++i){
    int c = q + 4*i;
    ob[(size_t)c*N_ + tok] = (tile[tok][c]-mu)*rstd*wls[c] + bls[c];
  }
}

// ---------------- weight pre-convert: fc1_w, fc2_w -> bf16 wbuf ----------------
__global__ __launch_bounds__(256) void k_wcvt(const float* __restrict__ w1,
    const float* __restrict__ w2, unsigned short* __restrict__ wb){
  const int TOT = HID_*C_;                 // 147456
  int base = (blockIdx.x*256 + threadIdx.x) * 8;
  const float* src = (base < TOT) ? (w1 + base) : (w2 + (base - TOT));
  float4 a = *reinterpret_cast<const float4*>(src);
  float4 b = *reinterpret_cast<const float4*>(src + 4);
  ushort4 p0, p1;
  p0.x=f2bf(a.x); p0.y=f2bf(a.y); p0.z=f2bf(a.z); p0.w=f2bf(a.w);
  p1.x=f2bf(b.x); p1.y=f2bf(b.y); p1.z=f2bf(b.z); p1.w=f2bf(b.w);
  *reinterpret_cast<ushort4*>(wb + base)     = p0;
  *reinterpret_cast<ushort4*>(wb + base + 4) = p1;
}

// ------- fc1 MFMA, A-reuse: block = 128-token m-tile, loop 12 n-tiles; B from bf16 wbuf -------
__global__ __launch_bounds__(256) void k_fc1(const float* __restrict__ ln2t,
    const unsigned short* __restrict__ wb1, const float* __restrict__ bias,
    unsigned short* __restrict__ h1, int b_off){
  int bid = blockIdx.x;
  int bl  = bid >> 7;
  int m0  = (bid & 127) * 128;
  int t = threadIdx.x, lane = t & 63;
  int wv = t >> 6, wm = wv & 1, wn = wv >> 1;
  int l15 = lane & 15, lhi = lane >> 4;
  __shared__ unsigned short Al[128][200];   // [m][c] bf16
  __shared__ unsigned short Bl[64][200];
  const float* a = ln2t + (size_t)(b_off+bl)*C_*N_ + m0;
  unsigned short* hb = h1 + (size_t)bl*HID_*N_;
  {
    int m = t & 127, half = t >> 7;
#pragma unroll
    for (int i = 0; i < 48; ++i){
      int p = half + 2*i;                    // 0..95
      float v0 = a[(size_t)(2*p)*N_ + m];
      float v1 = a[(size_t)(2*p+1)*N_ + m];
      unsigned u = (unsigned)f2bf(v0) | ((unsigned)f2bf(v1) << 16);
      *reinterpret_cast<unsigned*>(&Al[m][2*p]) = u;
    }
  }
  for (int nt = 0; nt < 12; ++nt){
    int n0 = nt*64;
    __syncthreads();
    {
#pragma unroll
      for (int i = 0; i < 6; ++i){
        int li = t + 256*i;                  // 0..1535 = 64 rows x 24 segs
        int row = li / 24, seg = li - row*24;
        *reinterpret_cast<uint4*>(&Bl[row][seg*8]) =
            *reinterpret_cast<const uint4*>(wb1 + (size_t)(n0+row)*C_ + seg*8);
      }
    }
    __syncthreads();
    f32x4 acc[4][2] = {};
#pragma unroll
    for (int ks = 0; ks < 6; ++ks){
      bf16x8 af[4], bfr[2];
#pragma unroll
      for (int mf = 0; mf < 4; ++mf)
        af[mf] = *reinterpret_cast<const bf16x8*>(&Al[wm*64 + mf*16 + l15][ks*32 + lhi*8]);
#pragma unroll
      for (int nf = 0; nf < 2; ++nf)
        bfr[nf] = *reinterpret_cast<const bf16x8*>(&Bl[wn*32 + nf*16 + l15][ks*32 + lhi*8]);
#pragma unroll
      for (int mf = 0; mf < 4; ++mf)
#pragma unroll
        for (int nf = 0; nf < 2; ++nf)
          acc[mf][nf] = __builtin_amdgcn_mfma_f32_16x16x32_bf16(af[mf], bfr[nf], acc[mf][nf], 0,0,0);
    }
#pragma unroll
    for (int mf = 0; mf < 4; ++mf){
      int mb = m0 + wm*64 + mf*16 + lhi*4;
#pragma unroll
      for (int nf = 0; nf < 2; ++nf){
        int n = n0 + wn*32 + nf*16 + l15;
        float bv = bias[n];
        ushort4 pk;
        pk.x = f2bf(acc[mf][nf][0] + bv);
        pk.y = f2bf(acc[mf][nf][1] + bv);
        pk.z = f2bf(acc[mf][nf][2] + bv);
        pk.w = f2bf(acc[mf][nf][3] + bv);
        *reinterpret_cast<ushort4*>(&hb[(size_t)n*N_ + mb]) = pk;
      }
    }
  }
}

// ------- depthwise 3x3 + exact GELU, one batch: h1 (HID,N) -> g (HID,N) -------
// block = one channel x 16 image rows; thread = 8 cols
__global__ __launch_bounds__(256) void k_conv(const unsigned short* __restrict__ h1,
    const float* __restrict__ dw, unsigned short* __restrict__ g){
  int bid = blockIdx.x;
  int strip = bid & 7;
  int ch    = bid >> 3;
  int t = threadIdx.x;
  int lr = t >> 4;                 // 0..15
  int j0 = (t & 15) * 8;
  int row = strip*16 + lr;
  const unsigned short* plane = h1 + (size_t)ch*N_;
  const float* wp = dw + (size_t)ch*9;
  float s[8] = {0.f,0.f,0.f,0.f,0.f,0.f,0.f,0.f};
#pragma unroll
  for (int dy = 0; dy < 3; ++dy){
    int rr = row - 1 + dy;
    if (rr < 0 || rr >= H_) continue;
    const unsigned short* rp = plane + rr*W_ + j0;
    bf16x8 mid = *reinterpret_cast<const bf16x8*>(rp);
    float v[10];
    v[0] = (j0 > 0)      ? bf2f(rp[-1]) : 0.f;
    v[9] = (j0 < W_ - 8) ? bf2f(rp[8])  : 0.f;
#pragma unroll
    for (int j = 0; j < 8; ++j) v[1+j] = bf2f((unsigned short)mid[j]);
    float wa = wp[3*dy], wb = wp[3*dy+1], wc = wp[3*dy+2];
#pragma unroll
    for (int j = 0; j < 8; ++j)
      s[j] += v[j]*wa + v[j+1]*wb + v[j+2]*wc;
  }
  unsigned short r8[8];
#pragma unroll
  for (int j = 0; j < 8; ++j){
    float xx = s[j];
    r8[j] = f2bf(0.5f*xx*(1.f + erff(xx*0.70710678f)));
  }
  *reinterpret_cast<uint4*>(g + (size_t)ch*N_ + row*W_ + j0) =
      *reinterpret_cast<const uint4*>(r8);
}

// ------- fc2 MFMA + bias + residual, one batch: g (HID,N) -> io (C,N) -------
// block = 32-token m-tile x full 192 n; K=768 chunked by 64
__global__ __launch_bounds__(256) void k_fc2(const unsigned short* __restrict__ g,
    const unsigned short* __restrict__ wb2, const float* __restrict__ bias,
    float* __restrict__ io){
  int m0 = blockIdx.x * 32;
  int t = threadIdx.x, lane = t & 63, wv = t >> 6;
  int l15 = lane & 15, lhi = lane >> 4;
  __shared__ unsigned short Al[32][72];
  __shared__ unsigned short Bl[192][72];
  const unsigned short* gb = g + m0;
  f32x4 acc[2][3] = {};
  int m = t & 31, pr = t >> 5;       // pr 0..7
  for (int k0 = 0; k0 < HID_; k0 += 64){
#pragma unroll
    for (int i = 0; i < 4; ++i){
      int p = pr + 8*i;              // 0..31 k-pairs
      unsigned short v0 = gb[(size_t)(k0+2*p)*N_ + m];
      unsigned short v1 = gb[(size_t)(k0+2*p+1)*N_ + m];
      *reinterpret_cast<unsigned*>(&Al[m][2*p]) = (unsigned)v0 | ((unsigned)v1 << 16);
    }
#pragma unroll
    for (int i = 0; i < 6; ++i){
      int li = t + 256*i;            // 0..1535 = 192 rows x 8 segs
      int row = li >> 3, seg = li & 7;
      *reinterpret_cast<uint4*>(&Bl[row][seg*8]) =
          *reinterpret_cast<const uint4*>(wb2 + (size_t)row*HID_ + k0 + seg*8);
    }
    __syncthreads();
#pragma unroll
    for (int ks = 0; ks < 2; ++ks){
      bf16x8 af[2], bfr[3];
#pragma unroll
      for (int mf = 0; mf < 2; ++mf)
        af[mf] = *reinterpret_cast<const bf16x8*>(&Al[mf*16 + l15][ks*32 + lhi*8]);
#pragma unroll
      for (int nf = 0; nf < 3; ++nf)
        bfr[nf] = *reinterpret_cast<const bf16x8*>(&Bl[wv*48 + nf*16 + l15][ks*32 + lhi*8]);
#pragma unroll
      for (int mf = 0; mf < 2; ++mf)
#pragma unroll
        for (int nf = 0; nf < 3; ++nf)
          acc[mf][nf] = __builtin_amdgcn_mfma_f32_16x16x32_bf16(af[mf], bfr[nf], acc[mf][nf], 0,0,0);
    }
    __syncthreads();
  }
#pragma unroll
  for (int mf = 0; mf < 2; ++mf){
    int tok = m0 + mf*16 + lhi*4;
#pragma unroll
    for (int nf = 0; nf < 3; ++nf){
      int oc = wv*48 + nf*16 + l15;
      float bv = bias[oc];
      size_t off = (size_t)oc*N_ + tok;
      float4 rr = *reinterpret_cast<const float4*>(io + off);
      float4 v = make_float4(rr.x + acc[mf][nf][0] + bv, rr.y + acc[mf][nf][1] + bv,
                             rr.z + acc[mf][nf][2] + bv, rr.w + acc[mf][nf][3] + bv);
      *reinterpret_cast<float4*>(io + off) = v;
    }
  }
}

extern "C" void kernel_launch(void* const* d_in, const int* in_sizes, int n_in,
                              void* d_out, int out_size, void* d_ws, size_t ws_size,
                              hipStream_t stream) {
  const float*    x      = (const float*)d_in[0];
  const unsigned* idx    = (const unsigned*)d_in[1];
  const float*    ln1_w  = (const float*)d_in[2];
  const float*    ln1_b  = (const float*)d_in[3];
  const float*    qkv_w  = (const float*)d_in[4];
  const float*    proj_w = (const float*)d_in[5];
  const float*    proj_b = (const float*)d_in[6];
  const float*    ln2_w  = (const float*)d_in[7];
  const float*    ln2_b  = (const float*)d_in[8];
  const float*    fc1_w  = (const float*)d_in[9];
  const float*    fc1_b  = (const float*)d_in[10];
  const float*    dw_w   = (const float*)d_in[11];
  const float*    fc2_w  = (const float*)d_in[12];
  const float*    fc2_b  = (const float*)d_in[13];
  float* out = (float*)d_out;          // doubles as ln2t (B,C,N) f32

  const size_t SZY = (size_t)N_*C_*4;
  const size_t SZQ = (size_t)K_*3*C_*2;
  const size_t SZA = (size_t)K_*C_*2;
  const size_t SZO = (size_t)NC_*HEADS_*K_*HD_*4;
  const size_t SZH = (size_t)HID_*N_*2;            // 25.17 MB (one batch h1/g)
  int nb = (ws_size >= (size_t)B_*SZH) ? B_ : 1;   // deterministic
  int mb = (nb == B_) ? 2 : 1;                     // batches per MLP pair

  char* ws = (char*)d_ws;
  float*          y    = (float*)ws;
  unsigned short* qkvb = (unsigned short*)(ws + (size_t)nb*SZY);
  unsigned short* aob  = (unsigned short*)(ws + (size_t)nb*(SZY+SZQ));
  float*          po   = (float*)(ws + (size_t)nb*(SZY+SZQ+SZA));
  float*          pml  = (float*)(ws + (size_t)nb*(SZY+SZQ+SZA+SZO));
  // MLP phase (front region dead): [h1 slots (mb)][g slot][wbuf bf16 weights]
  unsigned short* h1s  = (unsigned short*)ws;
  unsigned short* gs   = (unsigned short*)(ws + (size_t)mb*SZH);
  unsigned short* wbuf = (unsigned short*)(ws + (size_t)(mb+1)*SZH);
  unsigned short* wb1  = wbuf;
  unsigned short* wb2  = wbuf + (size_t)HID_*C_;

  for (int b0 = 0; b0 < B_; b0 += nb){
    k_ln1   <<<nb*256,             256, 0, stream>>>(x, ln1_w, ln1_b, y, b0);
    k_qkv   <<<nb*16*9,            256, 0, stream>>>(y, idx, qkv_w, qkvb, b0);
    k_attn  <<<nb*HEADS_*32*NC_,   256, 0, stream>>>(qkvb, po, pml, nb);
    k_amerge<<<nb*HEADS_*K_/4,     256, 0, stream>>>(po, pml, aob, nb);
    k_proj  <<<nb*16*3,            256, 0, stream>>>(aob, idx, proj_w, proj_b, y, b0);
    k_ln2   <<<nb*256,             256, 0, stream>>>(x, y, ln2_w, ln2_b, out, b0);
    k_wcvt  <<<2*HID_*C_/(256*8),  256, 0, stream>>>(fc1_w, fc2_w, wbuf);
    for (int p0 = b0; p0 < b0 + nb; p0 += mb){
      k_fc1 <<<mb*128, 256, 0, stream>>>(out, wb1, fc1_b, h1s, p0);
      for (int b = p0; b < p0 + mb; ++b){
        k_conv<<<HID_*8, 256, 0, stream>>>(h1s + (size_t)(b-p0)*HID_*N_, dw_w, gs);
        k_fc2 <<<N_/32,  256, 0, stream>>>(gs, wb2, fc2_b, out + (size_t)b*C_*N_);
      }
    }
  }
}

// Round 7
// 315.772 us; speedup vs baseline: 1.1206x; 1.1206x over previous
//
#include <hip/hip_runtime.h>

#define B_ 4
#define C_ 192
#define H_ 128
#define W_ 128
#define N_ (H_*W_)      // 16384
#define K_ 2048
#define HEADS_ 3
#define HD_ 64
#define HID_ 768
#define NC_ 4           // attention split-K chunks
#define KC_ (K_/NC_)    // 512

typedef __attribute__((ext_vector_type(4))) float f32x4;
typedef __attribute__((ext_vector_type(8))) short bf16x8;

__device__ __forceinline__ unsigned short f2bf(float f){
  unsigned int u = __float_as_uint(f);
  u += 0x7FFFu + ((u >> 16) & 1u);
  return (unsigned short)(u >> 16);
}
__device__ __forceinline__ float bf2f(unsigned short s){
  return __uint_as_float(((unsigned int)s) << 16);
}

__device__ __forceinline__ int load_idx(const unsigned* __restrict__ ip, int pos){
  bool is64 = (ip[1]==0u) & (ip[3]==0u) & (ip[5]==0u) & (ip[7]==0u);
  int v = is64 ? (int)ip[2*pos] : (int)ip[pos];
  return min(max(v, 0), N_-1);
}

// ---------------- LN1: x (B,C,N) -> y (nb,N,C); 256 thr, 4-way C-split ----------------
__global__ __launch_bounds__(256) void k_ln1(const float* __restrict__ x,
    const float* __restrict__ w, const float* __restrict__ bias,
    float* __restrict__ y, int b_off){
  int blk = blockIdx.x;
  int bl = blk >> 8;
  int b  = b_off + bl;
  int n0 = (blk & 255) * 64;
  int t  = threadIdx.x;
  int tok = t & 63, q = t >> 6;
  __shared__ float tile[64][C_+1];
  __shared__ float red[8][64];
  __shared__ float wls[C_], bls[C_];
  if (t < C_){ wls[t] = w[t]; bls[t] = bias[t]; }
  const float* xb = x + (size_t)b*C_*N_ + n0;
  float sum = 0.f, sq = 0.f;
#pragma unroll
  for (int i = 0; i < 48; ++i){
    int c = q + 4*i;
    float v = xb[(size_t)c*N_ + tok];
    tile[tok][c] = v;
    sum += v; sq += v*v;
  }
  red[q][tok] = sum; red[4+q][tok] = sq;
  __syncthreads();
  if (q == 0){
    float s  = red[0][tok]+red[1][tok]+red[2][tok]+red[3][tok];
    float s2 = red[4][tok]+red[5][tok]+red[6][tok]+red[7][tok];
    float mu = s*(1.f/C_);
    float rstd = rsqrtf(s2*(1.f/C_) - mu*mu + 1e-5f);
    red[0][tok] = mu; red[1][tok] = rstd;
  }
  __syncthreads();
  float* yb = y + ((size_t)bl*N_ + n0)*C_;
#pragma unroll
  for (int i = 0; i < 48; ++i){
    int li = t + 256*i;
    int tk = li / C_, c = li - tk*C_;
    yb[li] = (tile[tk][c]-red[0][tk])*red[1][tk]*wls[c] + bls[c];
  }
}

// ---------------- QKV MFMA GEMM with gather ----------------
__global__ __launch_bounds__(256) void k_qkv(const float* __restrict__ y,
    const unsigned* __restrict__ idx, const float* __restrict__ wq,
    unsigned short* __restrict__ qkv, int b_off){
  const int NT = (3*C_)/64;  // 9
  int bid = blockIdx.x;
  int bl  = bid / (16*NT);
  int rem = bid % (16*NT);
  int m0  = (rem / NT) * 128;
  int n0  = (rem % NT) * 64;
  int t = threadIdx.x, lane = t & 63;
  int wv = t >> 6, wm = wv & 1, wn = wv >> 1;
  __shared__ unsigned short Al[128][40];
  __shared__ unsigned short Bl[64][40];
  __shared__ int rows[128];
  if (t < 128) rows[t] = load_idx(idx, (b_off+bl)*K_ + m0 + t);
  __syncthreads();
  f32x4 acc[4][2] = {};
  int l15 = lane & 15, lhi = lane >> 4;
  for (int k0 = 0; k0 < C_; k0 += 32){
    {
      int m = t >> 1;
      const float* src = y + ((size_t)bl*N_ + rows[m])*C_ + k0;
#pragma unroll
      for (int i = 0; i < 4; ++i){
        int kq = (t & 1) + 2*i;
        float4 v = *reinterpret_cast<const float4*>(src + 4*kq);
        ushort4 p; p.x=f2bf(v.x); p.y=f2bf(v.y); p.z=f2bf(v.z); p.w=f2bf(v.w);
        *reinterpret_cast<ushort4*>(&Al[m][4*kq]) = p;
      }
      int n = t >> 2;
      const float* bsrc = wq + (size_t)(n0+n)*C_ + k0;
#pragma unroll
      for (int i = 0; i < 2; ++i){
        int q = (t & 3) + 4*i;
        float4 v = *reinterpret_cast<const float4*>(bsrc + 4*q);
        ushort4 p; p.x=f2bf(v.x); p.y=f2bf(v.y); p.z=f2bf(v.z); p.w=f2bf(v.w);
        *reinterpret_cast<ushort4*>(&Bl[n][4*q]) = p;
      }
    }
    __syncthreads();
    bf16x8 af[4], bfr[2];
#pragma unroll
    for (int mf = 0; mf < 4; ++mf)
      af[mf] = *reinterpret_cast<const bf16x8*>(&Al[wm*64 + mf*16 + l15][lhi*8]);
#pragma unroll
    for (int nf = 0; nf < 2; ++nf)
      bfr[nf] = *reinterpret_cast<const bf16x8*>(&Bl[wn*32 + nf*16 + l15][lhi*8]);
#pragma unroll
    for (int mf = 0; mf < 4; ++mf)
#pragma unroll
      for (int nf = 0; nf < 2; ++nf)
        acc[mf][nf] = __builtin_amdgcn_mfma_f32_16x16x32_bf16(af[mf], bfr[nf], acc[mf][nf], 0,0,0);
    __syncthreads();
  }
#pragma unroll
  for (int mf = 0; mf < 4; ++mf){
    int mb = m0 + wm*64 + mf*16 + lhi*4;
#pragma unroll
    for (int nf = 0; nf < 2; ++nf){
      int n = n0 + wn*32 + nf*16 + l15;
#pragma unroll
      for (int r = 0; r < 4; ++r)
        qkv[((size_t)bl*K_ + mb + r)*(3*C_) + n] = f2bf(acc[mf][nf][r]);
    }
  }
}

// ------- attention split-K, swapped QK^T (k-rows in regs, q lane-local) -------
__global__ __launch_bounds__(256) void k_attn(const unsigned short* __restrict__ qkv,
    float* __restrict__ po, float* __restrict__ pml, int nb){
  int bid = blockIdx.x;
  int c   = bid & (NC_-1);
  int qt  = (bid >> 2) & 31;
  int bh  = bid >> 7;
  int h = bh % HEADS_, bl = bh / HEADS_;
  int q0 = qt*64;
  int t = threadIdx.x, lane = t & 63, wv = t >> 6;
  int l15 = lane & 15, lhi = lane >> 4;
  const unsigned short* base = qkv + (size_t)bl*K_*(3*C_) + h*HD_;
  __shared__ unsigned short Ql[64][72];
  __shared__ unsigned short Kl[64][72];
  __shared__ unsigned short Vt[64][72];
  __shared__ unsigned short Pl[4][16][72];
  {
    int r = t >> 2, d0 = (t & 3) * 16;
    const uint4* src = reinterpret_cast<const uint4*>(base + (size_t)(q0+r)*(3*C_) + d0);
    *reinterpret_cast<uint4*>(&Ql[r][d0])   = src[0];
    *reinterpret_cast<uint4*>(&Ql[r][d0+8]) = src[1];
  }
  __syncthreads();
  float m_q = -1e30f, l_q = 0.f;    // stats for q = l15 (replicated over lhi)
  f32x4 o[4] = {};
  for (int kt0 = c*KC_; kt0 < c*KC_ + KC_; kt0 += 64){
    {
      int r = t >> 2, d0 = (t & 3) * 16;
      const uint4* src = reinterpret_cast<const uint4*>(base + (size_t)(kt0+r)*(3*C_) + C_ + d0);
      *reinterpret_cast<uint4*>(&Kl[r][d0])   = src[0];
      *reinterpret_cast<uint4*>(&Kl[r][d0+8]) = src[1];
      int kp = t & 31, vd0 = (t >> 5) * 8, k = 2*kp;
      const ushort4* v0 = reinterpret_cast<const ushort4*>(base + (size_t)(kt0+k)*(3*C_)   + 2*C_ + vd0);
      const ushort4* v1 = reinterpret_cast<const ushort4*>(base + (size_t)(kt0+k+1)*(3*C_) + 2*C_ + vd0);
      ushort4 a0 = v0[0], a1 = v0[1], b0 = v1[0], b1 = v1[1];
      unsigned short va[8] = {a0.x,a0.y,a0.z,a0.w,a1.x,a1.y,a1.z,a1.w};
      unsigned short vb[8] = {b0.x,b0.y,b0.z,b0.w,b1.x,b1.y,b1.z,b1.w};
#pragma unroll
      for (int j = 0; j < 8; ++j){
        unsigned u = (unsigned)va[j] | ((unsigned)vb[j] << 16);
        *reinterpret_cast<unsigned*>(&Vt[vd0+j][k]) = u;
      }
    }
    __syncthreads();
    // swapped QK^T: s[nt][reg] = S[k = nt*16+lhi*4+reg][q = l15]
    f32x4 s[4] = {};
#pragma unroll
    for (int kt = 0; kt < 2; ++kt){
      bf16x8 qf = *reinterpret_cast<const bf16x8*>(&Ql[wv*16 + l15][kt*32 + lhi*8]);
#pragma unroll
      for (int nt = 0; nt < 4; ++nt){
        bf16x8 kf = *reinterpret_cast<const bf16x8*>(&Kl[nt*16 + l15][kt*32 + lhi*8]);
        s[nt] = __builtin_amdgcn_mfma_f32_16x16x32_bf16(kf, qf, s[nt], 0,0,0);
      }
    }
    // online softmax: in-lane reduce over 16 k + 2 shfls across lhi
    float mx = s[0][0];
#pragma unroll
    for (int nt = 0; nt < 4; ++nt)
#pragma unroll
      for (int reg = 0; reg < 4; ++reg) mx = fmaxf(mx, s[nt][reg]);
    mx = fmaxf(mx, __shfl_xor(mx, 16));
    mx = fmaxf(mx, __shfl_xor(mx, 32));
    mx *= 0.125f;
    float mn = fmaxf(m_q, mx);
    float corr = __expf(m_q - mn);
    float ls = 0.f;
#pragma unroll
    for (int nt = 0; nt < 4; ++nt){
      float p0 = __expf(fmaf(s[nt][0], 0.125f, -mn));
      float p1 = __expf(fmaf(s[nt][1], 0.125f, -mn));
      float p2 = __expf(fmaf(s[nt][2], 0.125f, -mn));
      float p3 = __expf(fmaf(s[nt][3], 0.125f, -mn));
      ls += (p0 + p1) + (p2 + p3);
      unsigned uA = (unsigned)f2bf(p0) | ((unsigned)f2bf(p1) << 16);
      unsigned uB = (unsigned)f2bf(p2) | ((unsigned)f2bf(p3) << 16);
      int col = nt*16 + lhi*4;
      *reinterpret_cast<unsigned*>(&Pl[wv][l15][col])     = uA;
      *reinterpret_cast<unsigned*>(&Pl[wv][l15][col + 2]) = uB;
    }
    ls += __shfl_xor(ls, 16);
    ls += __shfl_xor(ls, 32);
    l_q = l_q*corr + ls;
    m_q = mn;
    __threadfence_block();     // order P ds_writes before same-wave ds_reads
    // broadcast corr to o's q-rows (q = lhi*4+reg lives at lane q)
    float cr[4];
#pragma unroll
    for (int reg = 0; reg < 4; ++reg) cr[reg] = __shfl(corr, lhi*4 + reg);
#pragma unroll
    for (int nt = 0; nt < 4; ++nt)
#pragma unroll
      for (int reg = 0; reg < 4; ++reg) o[nt][reg] *= cr[reg];
    // PV: O (16q x 64d) += P (16x64) * V (64x64)
#pragma unroll
    for (int kt = 0; kt < 2; ++kt){
      bf16x8 pa = *reinterpret_cast<const bf16x8*>(&Pl[wv][l15][kt*32 + lhi*8]);
#pragma unroll
      for (int nt = 0; nt < 4; ++nt){
        bf16x8 vb = *reinterpret_cast<const bf16x8*>(&Vt[nt*16 + l15][kt*32 + lhi*8]);
        o[nt] = __builtin_amdgcn_mfma_f32_16x16x32_bf16(pa, vb, o[nt], 0,0,0);
      }
    }
    __syncthreads();
  }
  int R = nb*HEADS_*K_;
  int rowb = (bl*HEADS_ + h)*K_;
#pragma unroll
  for (int reg = 0; reg < 4; ++reg){
    int rq = rowb + q0 + wv*16 + lhi*4 + reg;
#pragma unroll
    for (int nt = 0; nt < 4; ++nt)
      po[((size_t)c*R + rq)*HD_ + nt*16 + l15] = o[nt][reg];
  }
  if (lhi == 0){
    int rq = rowb + q0 + wv*16 + l15;
    *reinterpret_cast<float2*>(pml + 2*((size_t)c*R + rq)) = make_float2(m_q, l_q);
  }
}

// ---------------- merge split-K partials -> ao bf16 (bl,K,C) ----------------
__global__ __launch_bounds__(256) void k_amerge(const float* __restrict__ po,
    const float* __restrict__ pml, unsigned short* __restrict__ ao, int nb){
  int R = nb*HEADS_*K_;
  int row = blockIdx.x*4 + (threadIdx.x >> 6);
  int lane = threadIdx.x & 63;
  float m[NC_], l[NC_];
#pragma unroll
  for (int cc = 0; cc < NC_; ++cc){
    float2 v = *reinterpret_cast<const float2*>(pml + 2*((size_t)cc*R + row));
    m[cc] = v.x; l[cc] = v.y;
  }
  float M = fmaxf(fmaxf(m[0],m[1]), fmaxf(m[2],m[3]));
  float L = 0.f, o = 0.f;
#pragma unroll
  for (int cc = 0; cc < NC_; ++cc){
    float e = __expf(m[cc] - M);
    L += l[cc]*e;
    o += e * po[((size_t)cc*R + row)*HD_ + lane];
  }
  o /= L;
  int q = row & (K_-1);
  int bh = row >> 11;
  int h = bh % HEADS_, bl = bh / HEADS_;
  ao[((size_t)bl*K_ + q)*C_ + h*HD_ + lane] = f2bf(o);
}

// ---------------- proj MFMA GEMM + scatter into y (fp32) ----------------
__global__ __launch_bounds__(256) void k_proj(const unsigned short* __restrict__ ain,
    const unsigned* __restrict__ idx, const float* __restrict__ pw,
    const float* __restrict__ pb, float* __restrict__ y, int b_off){
  const int NT = C_/64;   // 3
  int bid = blockIdx.x;
  int bl  = bid / (16*NT);
  int rem = bid % (16*NT);
  int m0  = (rem / NT) * 128;
  int n0  = (rem % NT) * 64;
  int t = threadIdx.x, lane = t & 63;
  int wv = t >> 6, wm = wv & 1, wn = wv >> 1;
  __shared__ unsigned short Al[128][40];
  __shared__ unsigned short Bl[64][40];
  __shared__ int rows[128];
  if (t < 128) rows[t] = load_idx(idx, (b_off+bl)*K_ + m0 + t);
  __syncthreads();
  f32x4 acc[4][2] = {};
  int l15 = lane & 15, lhi = lane >> 4;
  for (int k0 = 0; k0 < C_; k0 += 32){
    {
      int m = t >> 1;
      const unsigned short* src = ain + ((size_t)bl*K_ + m0 + m)*C_ + k0;
#pragma unroll
      for (int i = 0; i < 4; ++i){
        int kq = (t & 1) + 2*i;
        *reinterpret_cast<ushort4*>(&Al[m][4*kq]) =
            *reinterpret_cast<const ushort4*>(src + 4*kq);
      }
      int n = t >> 2;
      const float* bsrc = pw + (size_t)(n0+n)*C_ + k0;
#pragma unroll
      for (int i = 0; i < 2; ++i){
        int q = (t & 3) + 4*i;
        float4 v = *reinterpret_cast<const float4*>(bsrc + 4*q);
        ushort4 p; p.x=f2bf(v.x); p.y=f2bf(v.y); p.z=f2bf(v.z); p.w=f2bf(v.w);
        *reinterpret_cast<ushort4*>(&Bl[n][4*q]) = p;
      }
    }
    __syncthreads();
    bf16x8 af[4], bfr[2];
#pragma unroll
    for (int mf = 0; mf < 4; ++mf)
      af[mf] = *reinterpret_cast<const bf16x8*>(&Al[wm*64 + mf*16 + l15][lhi*8]);
#pragma unroll
    for (int nf = 0; nf < 2; ++nf)
      bfr[nf] = *reinterpret_cast<const bf16x8*>(&Bl[wn*32 + nf*16 + l15][lhi*8]);
#pragma unroll
    for (int mf = 0; mf < 4; ++mf)
#pragma unroll
      for (int nf = 0; nf < 2; ++nf)
        acc[mf][nf] = __builtin_amdgcn_mfma_f32_16x16x32_bf16(af[mf], bfr[nf], acc[mf][nf], 0,0,0);
    __syncthreads();
  }
#pragma unroll
  for (int mf = 0; mf < 4; ++mf){
    int mb = wm*64 + mf*16 + lhi*4;
#pragma unroll
    for (int nf = 0; nf < 2; ++nf){
      int n = n0 + wn*32 + nf*16 + l15;
      float bv = pb[n];
#pragma unroll
      for (int r = 0; r < 4; ++r)
        y[((size_t)bl*N_ + rows[mb + r])*C_ + n] = acc[mf][nf][r] + bv;
    }
  }
}

// ---------------- residual + LN2 -> ln2t (B,C,N) [== d_out]; 256 thr ----------------
__global__ __launch_bounds__(256) void k_ln2(const float* __restrict__ x,
    const float* __restrict__ y, const float* __restrict__ w,
    const float* __restrict__ bias, float* __restrict__ ln2t, int b_off){
  int blk = blockIdx.x;
  int bl = blk >> 8;
  int b  = b_off + bl;
  int n0 = (blk & 255) * 64;
  int t  = threadIdx.x;
  int tok = t & 63, q = t >> 6;
  __shared__ float tile[64][C_+1];
  __shared__ float red[8][64];
  __shared__ float wls[C_], bls[C_];
  if (t < C_){ wls[t] = w[t]; bls[t] = bias[t]; }
  const float* yb = y + ((size_t)bl*N_ + n0)*C_;
#pragma unroll
  for (int i = 0; i < 48; ++i){
    int li = t + 256*i;
    int tk = li / C_, c = li - tk*C_;
    tile[tk][c] = yb[li];
  }
  __syncthreads();
  const float* xb = x + (size_t)b*C_*N_ + n0;
  float sum = 0.f, sq = 0.f;
#pragma unroll
  for (int i = 0; i < 48; ++i){
    int c = q + 4*i;
    float v = xb[(size_t)c*N_ + tok] + tile[tok][c];
    tile[tok][c] = v;
    sum += v; sq += v*v;
  }
  red[q][tok] = sum; red[4+q][tok] = sq;
  __syncthreads();
  if (q == 0){
    float s  = red[0][tok]+red[1][tok]+red[2][tok]+red[3][tok];
    float s2 = red[4][tok]+red[5][tok]+red[6][tok]+red[7][tok];
    float mu = s*(1.f/C_);
    float rstd = rsqrtf(s2*(1.f/C_) - mu*mu + 1e-5f);
    red[0][tok] = mu; red[1][tok] = rstd;
  }
  __syncthreads();
  float* ob = ln2t + (size_t)b*C_*N_ + n0;
  float mu = red[0][tok], rstd = red[1][tok];
#pragma unroll
  for (int i = 0; i < 48; ++i){
    int c = q + 4*i;
    ob[(size_t)c*N_ + tok] = (tile[tok][c]-mu)*rstd*wls[c] + bls[c];
  }
}

// ---------------- weight pre-convert: fc1_w, fc2_w -> bf16 wbuf ----------------
__global__ __launch_bounds__(256) void k_wcvt(const float* __restrict__ w1,
    const float* __restrict__ w2, unsigned short* __restrict__ wb){
  const int TOT = HID_*C_;                 // 147456
  int base = (blockIdx.x*256 + threadIdx.x) * 8;
  const float* src = (base < TOT) ? (w1 + base) : (w2 + (base - TOT));
  float4 a = *reinterpret_cast<const float4*>(src);
  float4 b = *reinterpret_cast<const float4*>(src + 4);
  ushort4 p0, p1;
  p0.x=f2bf(a.x); p0.y=f2bf(a.y); p0.z=f2bf(a.z); p0.w=f2bf(a.w);
  p1.x=f2bf(b.x); p1.y=f2bf(b.y); p1.z=f2bf(b.z); p1.w=f2bf(b.w);
  *reinterpret_cast<ushort4*>(wb + base)     = p0;
  *reinterpret_cast<ushort4*>(wb + base + 4) = p1;
}

// ------- fc1 MFMA: block = 128-token m-tile x 384-hid half, loop 6 n-tiles -------
__global__ __launch_bounds__(256) void k_fc1(const float* __restrict__ ln2t,
    const unsigned short* __restrict__ wb1, const float* __restrict__ bias,
    unsigned short* __restrict__ h1, int b_off){
  int bid = blockIdx.x;
  int bl  = bid >> 8;                  // pair-local batch
  int rem = bid & 255;
  int m0  = (rem >> 1) * 128;
  int nh  = (rem & 1) * 6;             // n-tile half
  int t = threadIdx.x, lane = t & 63;
  int wv = t >> 6, wm = wv & 1, wn = wv >> 1;
  int l15 = lane & 15, lhi = lane >> 4;
  __shared__ unsigned short Al[128][200];   // [m][c] bf16
  __shared__ unsigned short Bl[64][200];
  const float* a = ln2t + (size_t)(b_off+bl)*C_*N_ + m0;
  unsigned short* hb = h1 + (size_t)bl*HID_*N_;
  {
    int m = t & 127, half = t >> 7;
#pragma unroll
    for (int i = 0; i < 48; ++i){
      int p = half + 2*i;                    // 0..95
      float v0 = a[(size_t)(2*p)*N_ + m];
      float v1 = a[(size_t)(2*p+1)*N_ + m];
      unsigned u = (unsigned)f2bf(v0) | ((unsigned)f2bf(v1) << 16);
      *reinterpret_cast<unsigned*>(&Al[m][2*p]) = u;
    }
  }
  for (int nt = 0; nt < 6; ++nt){
    int n0 = (nh + nt)*64;
    __syncthreads();
    {
#pragma unroll
      for (int i = 0; i < 6; ++i){
        int li = t + 256*i;                  // 0..1535 = 64 rows x 24 segs
        int row = li / 24, seg = li - row*24;
        *reinterpret_cast<uint4*>(&Bl[row][seg*8]) =
            *reinterpret_cast<const uint4*>(wb1 + (size_t)(n0+row)*C_ + seg*8);
      }
    }
    __syncthreads();
    f32x4 acc[4][2] = {};
#pragma unroll
    for (int ks = 0; ks < 6; ++ks){
      bf16x8 af[4], bfr[2];
#pragma unroll
      for (int mf = 0; mf < 4; ++mf)
        af[mf] = *reinterpret_cast<const bf16x8*>(&Al[wm*64 + mf*16 + l15][ks*32 + lhi*8]);
#pragma unroll
      for (int nf = 0; nf < 2; ++nf)
        bfr[nf] = *reinterpret_cast<const bf16x8*>(&Bl[wn*32 + nf*16 + l15][ks*32 + lhi*8]);
#pragma unroll
      for (int mf = 0; mf < 4; ++mf)
#pragma unroll
        for (int nf = 0; nf < 2; ++nf)
          acc[mf][nf] = __builtin_amdgcn_mfma_f32_16x16x32_bf16(af[mf], bfr[nf], acc[mf][nf], 0,0,0);
    }
#pragma unroll
    for (int mf = 0; mf < 4; ++mf){
      int mb = m0 + wm*64 + mf*16 + lhi*4;
#pragma unroll
      for (int nf = 0; nf < 2; ++nf){
        int n = n0 + wn*32 + nf*16 + l15;
        float bv = bias[n];
        ushort4 pk;
        pk.x = f2bf(acc[mf][nf][0] + bv);
        pk.y = f2bf(acc[mf][nf][1] + bv);
        pk.z = f2bf(acc[mf][nf][2] + bv);
        pk.w = f2bf(acc[mf][nf][3] + bv);
        *reinterpret_cast<ushort4*>(&hb[(size_t)n*N_ + mb]) = pk;
      }
    }
  }
}

// ------- depthwise 3x3 + exact GELU, one batch: h1 (HID,N) -> g (HID,N) -------
__global__ __launch_bounds__(256) void k_conv(const unsigned short* __restrict__ h1,
    const float* __restrict__ dw, unsigned short* __restrict__ g){
  int bid = blockIdx.x;
  int strip = bid & 7;
  int ch    = bid >> 3;
  int t = threadIdx.x;
  int lr = t >> 4;                 // 0..15
  int j0 = (t & 15) * 8;
  int row = strip*16 + lr;
  const unsigned short* plane = h1 + (size_t)ch*N_;
  const float* wp = dw + (size_t)ch*9;
  float s[8] = {0.f,0.f,0.f,0.f,0.f,0.f,0.f,0.f};
#pragma unroll
  for (int dy = 0; dy < 3; ++dy){
    int rr = row - 1 + dy;
    if (rr < 0 || rr >= H_) continue;
    const unsigned short* rp = plane + rr*W_ + j0;
    bf16x8 mid = *reinterpret_cast<const bf16x8*>(rp);
    float v[10];
    v[0] = (j0 > 0)      ? bf2f(rp[-1]) : 0.f;
    v[9] = (j0 < W_ - 8) ? bf2f(rp[8])  : 0.f;
#pragma unroll
    for (int j = 0; j < 8; ++j) v[1+j] = bf2f((unsigned short)mid[j]);
    float wa = wp[3*dy], wb = wp[3*dy+1], wc = wp[3*dy+2];
#pragma unroll
    for (int j = 0; j < 8; ++j)
      s[j] += v[j]*wa + v[j+1]*wb + v[j+2]*wc;
  }
  unsigned short r8[8];
#pragma unroll
  for (int j = 0; j < 8; ++j){
    float xx = s[j];
    r8[j] = f2bf(0.5f*xx*(1.f + erff(xx*0.70710678f)));
  }
  *reinterpret_cast<uint4*>(g + (size_t)ch*N_ + row*W_ + j0) =
      *reinterpret_cast<const uint4*>(r8);
}

// ------- fc2 MFMA + bias + residual, one batch: g (HID,N) -> io (C,N) -------
__global__ __launch_bounds__(256) void k_fc2(const unsigned short* __restrict__ g,
    const unsigned short* __restrict__ wb2, const float* __restrict__ bias,
    float* __restrict__ io){
  int m0 = blockIdx.x * 32;
  int t = threadIdx.x, lane = t & 63, wv = t >> 6;
  int l15 = lane & 15, lhi = lane >> 4;
  __shared__ unsigned short Al[32][72];
  __shared__ unsigned short Bl[192][72];
  const unsigned short* gb = g + m0;
  f32x4 acc[2][3] = {};
  int m = t & 31, pr = t >> 5;       // pr 0..7
  for (int k0 = 0; k0 < HID_; k0 += 64){
#pragma unroll
    for (int i = 0; i < 4; ++i){
      int p = pr + 8*i;              // 0..31 k-pairs
      unsigned short v0 = gb[(size_t)(k0+2*p)*N_ + m];
      unsigned short v1 = gb[(size_t)(k0+2*p+1)*N_ + m];
      *reinterpret_cast<unsigned*>(&Al[m][2*p]) = (unsigned)v0 | ((unsigned)v1 << 16);
    }
#pragma unroll
    for (int i = 0; i < 6; ++i){
      int li = t + 256*i;            // 0..1535 = 192 rows x 8 segs
      int row = li >> 3, seg = li & 7;
      *reinterpret_cast<uint4*>(&Bl[row][seg*8]) =
          *reinterpret_cast<const uint4*>(wb2 + (size_t)row*HID_ + k0 + seg*8);
    }
    __syncthreads();
#pragma unroll
    for (int ks = 0; ks < 2; ++ks){
      bf16x8 af[2], bfr[3];
#pragma unroll
      for (int mf = 0; mf < 2; ++mf)
        af[mf] = *reinterpret_cast<const bf16x8*>(&Al[mf*16 + l15][ks*32 + lhi*8]);
#pragma unroll
      for (int nf = 0; nf < 3; ++nf)
        bfr[nf] = *reinterpret_cast<const bf16x8*>(&Bl[wv*48 + nf*16 + l15][ks*32 + lhi*8]);
#pragma unroll
      for (int mf = 0; mf < 2; ++mf)
#pragma unroll
        for (int nf = 0; nf < 3; ++nf)
          acc[mf][nf] = __builtin_amdgcn_mfma_f32_16x16x32_bf16(af[mf], bfr[nf], acc[mf][nf], 0,0,0);
    }
    __syncthreads();
  }
#pragma unroll
  for (int mf = 0; mf < 2; ++mf){
    int tok = m0 + mf*16 + lhi*4;
#pragma unroll
    for (int nf = 0; nf < 3; ++nf){
      int oc = wv*48 + nf*16 + l15;
      float bv = bias[oc];
      size_t off = (size_t)oc*N_ + tok;
      float4 rr = *reinterpret_cast<const float4*>(io + off);
      float4 v = make_float4(rr.x + acc[mf][nf][0] + bv, rr.y + acc[mf][nf][1] + bv,
                             rr.z + acc[mf][nf][2] + bv, rr.w + acc[mf][nf][3] + bv);
      *reinterpret_cast<float4*>(io + off) = v;
    }
  }
}

extern "C" void kernel_launch(void* const* d_in, const int* in_sizes, int n_in,
                              void* d_out, int out_size, void* d_ws, size_t ws_size,
                              hipStream_t stream) {
  const float*    x      = (const float*)d_in[0];
  const unsigned* idx    = (const unsigned*)d_in[1];
  const float*    ln1_w  = (const float*)d_in[2];
  const float*    ln1_b  = (const float*)d_in[3];
  const float*    qkv_w  = (const float*)d_in[4];
  const float*    proj_w = (const float*)d_in[5];
  const float*    proj_b = (const float*)d_in[6];
  const float*    ln2_w  = (const float*)d_in[7];
  const float*    ln2_b  = (const float*)d_in[8];
  const float*    fc1_w  = (const float*)d_in[9];
  const float*    fc1_b  = (const float*)d_in[10];
  const float*    dw_w   = (const float*)d_in[11];
  const float*    fc2_w  = (const float*)d_in[12];
  const float*    fc2_b  = (const float*)d_in[13];
  float* out = (float*)d_out;          // doubles as ln2t (B,C,N) f32

  const size_t SZY = (size_t)N_*C_*4;
  const size_t SZQ = (size_t)K_*3*C_*2;
  const size_t SZA = (size_t)K_*C_*2;
  const size_t SZO = (size_t)NC_*HEADS_*K_*HD_*4;
  const size_t SZH = (size_t)HID_*N_*2;            // 25.17 MB (one batch h1/g)
  int nb = (ws_size >= (size_t)B_*SZH) ? B_ : 1;   // deterministic
  int mb = (nb == B_) ? 2 : 1;                     // batches per MLP pair

  char* ws = (char*)d_ws;
  float*          y    = (float*)ws;
  unsigned short* qkvb = (unsigned short*)(ws + (size_t)nb*SZY);
  unsigned short* aob  = (unsigned short*)(ws + (size_t)nb*(SZY+SZQ));
  float*          po   = (float*)(ws + (size_t)nb*(SZY+SZQ+SZA));
  float*          pml  = (float*)(ws + (size_t)nb*(SZY+SZQ+SZA+SZO));
  // MLP phase (front region dead): [h1 slots (mb)][g slot][wbuf bf16 weights]
  unsigned short* h1s  = (unsigned short*)ws;
  unsigned short* gs   = (unsigned short*)(ws + (size_t)mb*SZH);
  unsigned short* wbuf = (unsigned short*)(ws + (size_t)(mb+1)*SZH);
  unsigned short* wb1  = wbuf;
  unsigned short* wb2  = wbuf + (size_t)HID_*C_;

  for (int b0 = 0; b0 < B_; b0 += nb){
    k_ln1   <<<nb*256,             256, 0, stream>>>(x, ln1_w, ln1_b, y, b0);
    k_qkv   <<<nb*16*9,            256, 0, stream>>>(y, idx, qkv_w, qkvb, b0);
    k_attn  <<<nb*HEADS_*32*NC_,   256, 0, stream>>>(qkvb, po, pml, nb);
    k_amerge<<<nb*HEADS_*K_/4,     256, 0, stream>>>(po, pml, aob, nb);
    k_proj  <<<nb*16*3,            256, 0, stream>>>(aob, idx, proj_w, proj_b, y, b0);
    k_ln2   <<<nb*256,             256, 0, stream>>>(x, y, ln2_w, ln2_b, out, b0);
    k_wcvt  <<<2*HID_*C_/(256*8),  256, 0, stream>>>(fc1_w, fc2_w, wbuf);
    for (int p0 = b0; p0 < b0 + nb; p0 += mb){
      k_fc1 <<<mb*256, 256, 0, stream>>>(out, wb1, fc1_b, h1s, p0);
      for (int b = p0; b < p0 + mb; ++b){
        k_conv<<<HID_*8, 256, 0, stream>>>(h1s + (size_t)(b-p0)*HID_*N_, dw_w, gs);
        k_fc2 <<<N_/32,  256, 0, stream>>>(gs, wb2, fc2_b, out + (size_t)b*C_*N_);
      }
    }
  }
}